// Round 1
// baseline (530.497 us; speedup 1.0000x reference)
//
#include <hip/hip_runtime.h>
#include <stdint.h>

// MResConv on MI355X: two MeshCNN convs as bf16 MFMA GEMMs + fused BN stats.
// ws layout (bytes):
//   xT   [B][E][128] bf16      @ 0          (30,720,000)
//   Wf0  [20][256][32] bf16    @ 30720000   (327,680)
//   Wf1  [40][256][32] bf16    @ 31047680   (655,360)
//   x1   frag-blocked bf16     @ 31703040   (61,472,768)
//   rT   [B][E][256] bf16      @ 93175808   (61,440,000)
//   part [1876][2][256] f32    @ 154615808  (3,842,048)
//   ss   [2][256] f32          @ 158457856  (2,048)
// total ~158.5 MB

#define BB 4
#define CIN 128
#define COUT 256
#define EE 30000
#define BN 64
#define NTILES 469          // ceil(30000/64)
#define BC 64
#define KCH 320             // 5*BC K-values per chunk
#define PITCH 328           // KCH + 8 (bf16) -> 656B rows, 16B aligned, bank-spread
#define NBLK (NTILES * BB)  // 1876

typedef __attribute__((ext_vector_type(8))) short bf16x8;
typedef __attribute__((ext_vector_type(4))) float f32x4;

static __device__ __forceinline__ unsigned f2bf1(float f) {
    union { float f; unsigned u; } v; v.f = f;
    return (v.u + 0x7fffu + ((v.u >> 16) & 1u)) >> 16;   // RNE
}
static __device__ __forceinline__ unsigned pack2(float lo, float hi) {
    return f2bf1(lo) | (f2bf1(hi) << 16);
}
static __device__ __forceinline__ float bf2f(unsigned h) {
    union { unsigned u; float f; } v; v.u = h << 16;
    return v.f;
}

union RowU { int4 i4[2]; unsigned u[8]; };
union F16U { float4 f4[4]; float f[16]; };

// ---------------- transpose + cast: x[B,C,E] f32 -> xT[B,E,C] bf16 ----------
__global__ __launch_bounds__(256) void k_transpose(const float* __restrict__ x,
                                                   unsigned short* __restrict__ xT) {
    __shared__ float tile[64][CIN + 1];
    const int t = threadIdx.x;
    const int e0 = blockIdx.x * 64;
    const int b = blockIdx.y;
    const int el = t & 63;
    const bool ok = (e0 + el) < EE;
    const float* xb = x + (size_t)b * CIN * EE;
#pragma unroll
    for (int cc = 0; cc < CIN / 4; ++cc) {
        const int c = cc * 4 + (t >> 6);
        tile[el][c] = ok ? xb[(size_t)c * EE + e0 + el] : 0.f;
    }
    __syncthreads();
    const int el2 = t >> 2, cq = t & 3;
    if (e0 + el2 < EE) {
        unsigned ov[16];
#pragma unroll
        for (int i = 0; i < 16; ++i)
            ov[i] = pack2(tile[el2][cq * 32 + 2 * i], tile[el2][cq * 32 + 2 * i + 1]);
        int4* dst = (int4*)(xT + ((size_t)b * EE + e0 + el2) * CIN + cq * 32);
#pragma unroll
        for (int j = 0; j < 4; ++j)
            dst[j] = make_int4((int)ov[4 * j], (int)ov[4 * j + 1], (int)ov[4 * j + 2], (int)ov[4 * j + 3]);
    }
}

// ------------- W repack: W[m][c][k] f32 -> Wf[G/32][m][G%32] bf16 -----------
// K-order: G = chunk*KCH + k*BC + (c - chunk*BC), chunk = c/BC
__global__ __launch_bounds__(256) void k_wprep(const float* __restrict__ W,
                                               unsigned short* __restrict__ Wf,
                                               int C, int K) {
    const int id = blockIdx.x * 256 + threadIdx.x;
    if (id >= 256 * K) return;
    const int m = id / K;
    const int G = id % K;
    const int chunk = G / KCH;
    const int r = G % KCH;
    const int k = r / BC;
    const int c = chunk * BC + (r % BC);
    const float val = W[((size_t)m * C + c) * 5 + k];
    Wf[((size_t)(G / 32) * 256 + m) * 32 + (G % 32)] = (unsigned short)f2bf1(val);
}

// -------------------------- BN stats finalize -------------------------------
__global__ __launch_bounds__(256) void k_stats(const float* __restrict__ partials,
                                               const float* __restrict__ gamma,
                                               const float* __restrict__ beta,
                                               float* __restrict__ ss) {
    const int ch = blockIdx.x;
    const int t = threadIdx.x;
    float s = 0.f, q = 0.f;
    for (int i = t; i < NBLK; i += 256) {
        s += partials[(size_t)i * 512 + ch];
        q += partials[(size_t)i * 512 + 256 + ch];
    }
    __shared__ float ls[256], lq[256];
    ls[t] = s; lq[t] = q;
    __syncthreads();
    for (int off = 128; off > 0; off >>= 1) {
        if (t < off) { ls[t] += ls[t + off]; lq[t] += lq[t + off]; }
        __syncthreads();
    }
    if (t == 0) {
        const float inv = 1.f / (float)(BB * EE);
        const float mean = ls[0] * inv;
        const float var = lq[0] * inv - mean * mean;
        const float sc = gamma[ch] * rsqrtf(var + 1e-5f);
        ss[ch] = sc;
        ss[COUT + ch] = beta[ch] - mean * sc;
    }
}

// --------------------------- fused mesh-conv GEMM ---------------------------
// BM=256 (all out channels), BN=64 edges, 4 waves each 64x64.
// IS1=0: conv0 (writes x1 frag-blocked, rT=relu(x1), stat partials)
// IS1=1: conv1 (gathers rT + affine, adds x1 residual, relu, f32 out)
template <int C, int CHUNKS, int IS1>
__global__ __launch_bounds__(256) void k_conv(
    const unsigned short* __restrict__ xin,
    const int* __restrict__ gmm,
    const unsigned short* __restrict__ Wf,
    const float* __restrict__ ss,
    unsigned short* __restrict__ x1,
    unsigned short* __restrict__ rT,
    float* __restrict__ partials,
    float* __restrict__ out) {
    __shared__ unsigned short f_lds[64 * PITCH];
    const int t = threadIdx.x;
    const int w = t >> 6, lane = t & 63;
    const int ml = lane & 15, g = lane >> 4;
    const int tile = blockIdx.x, b = blockIdx.y;
    const int e0 = tile * BN;

    // build roles: 4 threads per edge, each owns 16 channels of each chunk
    const int be = t >> 2, bq = t & 3;
    const int eb = e0 + be;
    const int ec = (eb < EE) ? eb : 0;
    const int4 nb = *(const int4*)(gmm + ((size_t)b * EE + ec) * 4);

    const unsigned short* xb = xin + (size_t)b * EE * C;
    const unsigned short* rowc = xb + (size_t)ec * C;
    const unsigned short* row1 = xb + (size_t)nb.x * C;
    const unsigned short* row2 = xb + (size_t)nb.y * C;
    const unsigned short* row3 = xb + (size_t)nb.z * C;
    const unsigned short* row4 = xb + (size_t)nb.w * C;

    f32x4 acc[4][4];
#pragma unroll
    for (int i = 0; i < 4; ++i)
#pragma unroll
        for (int j = 0; j < 4; ++j)
            acc[i][j] = (f32x4){0.f, 0.f, 0.f, 0.f};

#pragma unroll 1
    for (int chunk = 0; chunk < CHUNKS; ++chunk) {
        const int cb = chunk * BC + bq * 16;

        F16U sc, sh;
        if (IS1) {
#pragma unroll
            for (int q = 0; q < 4; ++q) {
                sc.f4[q] = *(const float4*)(ss + cb + 4 * q);
                sh.f4[q] = *(const float4*)(ss + COUT + cb + 4 * q);
            }
        }

        unsigned o0[8], o1[8], o2[8], o3[8], o4[8];
        {   // neighbors 1 & 3
            RowU va, vb;
            va.i4[0] = *(const int4*)(row1 + cb); va.i4[1] = *(const int4*)(row1 + cb + 8);
            vb.i4[0] = *(const int4*)(row3 + cb); vb.i4[1] = *(const int4*)(row3 + cb + 8);
#pragma unroll
            for (int j = 0; j < 8; ++j) {
                float a0 = bf2f(va.u[j] & 0xffffu), a1 = bf2f(va.u[j] >> 16);
                float b0 = bf2f(vb.u[j] & 0xffffu), b1 = bf2f(vb.u[j] >> 16);
                if (IS1) {
                    a0 = fmaf(a0, sc.f[2 * j], sh.f[2 * j]); a1 = fmaf(a1, sc.f[2 * j + 1], sh.f[2 * j + 1]);
                    b0 = fmaf(b0, sc.f[2 * j], sh.f[2 * j]); b1 = fmaf(b1, sc.f[2 * j + 1], sh.f[2 * j + 1]);
                }
                o1[j] = pack2(a0 + b0, a1 + b1);
                o3[j] = pack2(fabsf(a0 - b0), fabsf(a1 - b1));
            }
        }
        {   // neighbors 2 & 4
            RowU va, vb;
            va.i4[0] = *(const int4*)(row2 + cb); va.i4[1] = *(const int4*)(row2 + cb + 8);
            vb.i4[0] = *(const int4*)(row4 + cb); vb.i4[1] = *(const int4*)(row4 + cb + 8);
#pragma unroll
            for (int j = 0; j < 8; ++j) {
                float a0 = bf2f(va.u[j] & 0xffffu), a1 = bf2f(va.u[j] >> 16);
                float b0 = bf2f(vb.u[j] & 0xffffu), b1 = bf2f(vb.u[j] >> 16);
                if (IS1) {
                    a0 = fmaf(a0, sc.f[2 * j], sh.f[2 * j]); a1 = fmaf(a1, sc.f[2 * j + 1], sh.f[2 * j + 1]);
                    b0 = fmaf(b0, sc.f[2 * j], sh.f[2 * j]); b1 = fmaf(b1, sc.f[2 * j + 1], sh.f[2 * j + 1]);
                }
                o2[j] = pack2(a0 + b0, a1 + b1);
                o4[j] = pack2(fabsf(a0 - b0), fabsf(a1 - b1));
            }
        }
        {   // center
            RowU v;
            v.i4[0] = *(const int4*)(rowc + cb); v.i4[1] = *(const int4*)(rowc + cb + 8);
#pragma unroll
            for (int j = 0; j < 8; ++j) {
                float c0 = bf2f(v.u[j] & 0xffffu), c1 = bf2f(v.u[j] >> 16);
                if (IS1) {
                    c0 = fmaf(c0, sc.f[2 * j], sh.f[2 * j]); c1 = fmaf(c1, sc.f[2 * j + 1], sh.f[2 * j + 1]);
                }
                o0[j] = pack2(c0, c1);
            }
        }

        __syncthreads();   // previous chunk's MFMA reads done
        {
            unsigned short* bp = &f_lds[be * PITCH + bq * 16];
            *(int4*)(bp + 0 * BC)     = make_int4((int)o0[0], (int)o0[1], (int)o0[2], (int)o0[3]);
            *(int4*)(bp + 0 * BC + 8) = make_int4((int)o0[4], (int)o0[5], (int)o0[6], (int)o0[7]);
            *(int4*)(bp + 1 * BC)     = make_int4((int)o1[0], (int)o1[1], (int)o1[2], (int)o1[3]);
            *(int4*)(bp + 1 * BC + 8) = make_int4((int)o1[4], (int)o1[5], (int)o1[6], (int)o1[7]);
            *(int4*)(bp + 2 * BC)     = make_int4((int)o2[0], (int)o2[1], (int)o2[2], (int)o2[3]);
            *(int4*)(bp + 2 * BC + 8) = make_int4((int)o2[4], (int)o2[5], (int)o2[6], (int)o2[7]);
            *(int4*)(bp + 3 * BC)     = make_int4((int)o3[0], (int)o3[1], (int)o3[2], (int)o3[3]);
            *(int4*)(bp + 3 * BC + 8) = make_int4((int)o3[4], (int)o3[5], (int)o3[6], (int)o3[7]);
            *(int4*)(bp + 4 * BC)     = make_int4((int)o4[0], (int)o4[1], (int)o4[2], (int)o4[3]);
            *(int4*)(bp + 4 * BC + 8) = make_int4((int)o4[4], (int)o4[5], (int)o4[6], (int)o4[7]);
        }
        __syncthreads();

        const unsigned short* wp = Wf + (size_t)chunk * (KCH / 32) * COUT * 32;
#pragma unroll 2
        for (int kk = 0; kk < KCH / 32; ++kk) {
            union { int4 i; bf16x8 h; } af[4], bfr[4];
#pragma unroll
            for (int fm = 0; fm < 4; ++fm)
                af[fm].i = *(const int4*)(wp + ((size_t)kk * COUT + (w * 64 + fm * 16 + ml)) * 32 + g * 8);
#pragma unroll
            for (int fn = 0; fn < 4; ++fn)
                bfr[fn].i = *(const int4*)&f_lds[(fn * 16 + ml) * PITCH + kk * 32 + g * 8];
#pragma unroll
            for (int fm = 0; fm < 4; ++fm)
#pragma unroll
                for (int fn = 0; fn < 4; ++fn)
                    acc[fm][fn] = __builtin_amdgcn_mfma_f32_16x16x32_bf16(af[fm].h, bfr[fn].h, acc[fm][fn], 0, 0, 0);
        }
    }

    // ------------------------------ epilogue --------------------------------
    const size_t fragbase = (((size_t)b * NTILES + tile) * 4 + w) * 16;
    if (!IS1) {
#pragma unroll
        for (int fm = 0; fm < 4; ++fm) {
#pragma unroll
            for (int fn = 0; fn < 4; ++fn) {
                const int fi = fm * 4 + fn;
                uint2 pk;
                pk.x = pack2(acc[fm][fn][0], acc[fm][fn][1]);
                pk.y = pack2(acc[fm][fn][2], acc[fm][fn][3]);
                *(uint2*)(x1 + (fragbase + fi) * 256 + lane * 4) = pk;   // coalesced
                const int e = e0 + fn * 16 + ml;
                if (e < EE) {
                    uint2 pr;
                    pr.x = pack2(fmaxf(acc[fm][fn][0], 0.f), fmaxf(acc[fm][fn][1], 0.f));
                    pr.y = pack2(fmaxf(acc[fm][fn][2], 0.f), fmaxf(acc[fm][fn][3], 0.f));
                    *(uint2*)(rT + ((size_t)b * EE + e) * COUT + w * 64 + fm * 16 + g * 4) = pr;
                }
            }
        }
        // BN stat partials: reduce over the 16 e-lanes, one (ch) per lane
        float ks = 0.f, kq = 0.f;
#pragma unroll
        for (int fm = 0; fm < 4; ++fm) {
#pragma unroll
            for (int r = 0; r < 4; ++r) {
                float s = 0.f, q2 = 0.f;
#pragma unroll
                for (int fn = 0; fn < 4; ++fn) {
                    const int e = e0 + fn * 16 + ml;
                    const float v = (e < EE) ? fmaxf(acc[fm][fn][r], 0.f) : 0.f;
                    s += v; q2 += v * v;
                }
                s += __shfl_xor(s, 1); s += __shfl_xor(s, 2);
                s += __shfl_xor(s, 4); s += __shfl_xor(s, 8);
                q2 += __shfl_xor(q2, 1); q2 += __shfl_xor(q2, 2);
                q2 += __shfl_xor(q2, 4); q2 += __shfl_xor(q2, 8);
                if (ml == fm * 4 + r) { ks = s; kq = q2; }
            }
        }
        const int ch = w * 64 + (ml >> 2) * 16 + g * 4 + (ml & 3);
        float* pp = partials + ((size_t)b * NTILES + tile) * 512;
        pp[ch] = ks;
        pp[256 + ch] = kq;
    } else {
#pragma unroll
        for (int fm = 0; fm < 4; ++fm) {
#pragma unroll
            for (int fn = 0; fn < 4; ++fn) {
                const int fi = fm * 4 + fn;
                const uint2 pk = *(const uint2*)(x1 + (fragbase + fi) * 256 + lane * 4);
                const int e = e0 + fn * 16 + ml;
                if (e < EE) {
                    const int chb = w * 64 + fm * 16 + g * 4;
                    float* op = out + ((size_t)b * COUT + chb) * EE + e;
                    op[0]              = fmaxf(acc[fm][fn][0] + bf2f(pk.x & 0xffffu), 0.f);
                    op[(size_t)EE]     = fmaxf(acc[fm][fn][1] + bf2f(pk.x >> 16), 0.f);
                    op[(size_t)2 * EE] = fmaxf(acc[fm][fn][2] + bf2f(pk.y & 0xffffu), 0.f);
                    op[(size_t)3 * EE] = fmaxf(acc[fm][fn][3] + bf2f(pk.y >> 16), 0.f);
                }
            }
        }
    }
}

extern "C" void kernel_launch(void* const* d_in, const int* in_sizes, int n_in,
                              void* d_out, int out_size, void* d_ws, size_t ws_size,
                              hipStream_t stream) {
    const float* x = (const float*)d_in[0];
    const int* gmm = (const int*)d_in[1];
    const float* W0 = (const float*)d_in[2];
    const float* gamma = (const float*)d_in[3];
    const float* beta = (const float*)d_in[4];
    const float* W1 = (const float*)d_in[5];
    float* out = (float*)d_out;

    char* ws = (char*)d_ws;
    unsigned short* xT  = (unsigned short*)(ws);
    unsigned short* Wf0 = (unsigned short*)(ws + 30720000);
    unsigned short* Wf1 = (unsigned short*)(ws + 31047680);
    unsigned short* x1  = (unsigned short*)(ws + 31703040);
    unsigned short* rT  = (unsigned short*)(ws + 93175808);
    float* partials     = (float*)(ws + 154615808);
    float* ss           = (float*)(ws + 158457856);

    k_transpose<<<dim3(NTILES, BB), 256, 0, stream>>>(x, xT);
    k_wprep<<<dim3(640), 256, 0, stream>>>(W0, Wf0, CIN, 640);
    k_wprep<<<dim3(1280), 256, 0, stream>>>(W1, Wf1, COUT, 1280);
    k_conv<CIN, 2, 0><<<dim3(NTILES, BB), 256, 0, stream>>>(
        xT, gmm, Wf0, nullptr, x1, rT, partials, nullptr);
    k_stats<<<dim3(256), 256, 0, stream>>>(partials, gamma, beta, ss);
    k_conv<COUT, 4, 1><<<dim3(NTILES, BB), 256, 0, stream>>>(
        rT, gmm, Wf1, ss, x1, nullptr, nullptr, out);
}

// Round 2
// 478.161 us; speedup vs baseline: 1.1095x; 1.1095x over previous
//
#include <hip/hip_runtime.h>
#include <hip/hip_bf16.h>
#include <stdint.h>

// MResConv on MI355X: two MeshCNN convs as bf16 MFMA GEMMs + fused BN stats.
// R2: cvt_pk bf16 packing, BN-affine folded into W1+bias, depth-2 gather
//     pipeline, XCD batch-affinity swizzle.
// ws layout (bytes):
//   xT   [B][E][128] bf16      @ 0          (30,720,000)
//   Wf0  [20][256][32] bf16    @ 30720000   (327,680)
//   Wf1  [40][256][32] bf16    @ 31047680   (655,360)
//   x1   frag-blocked bf16     @ 31703040   (61,472,768)
//   rT   [B][E][256] bf16      @ 93175808   (61,440,000)
//   part [1876][2][256] f32    @ 154615808  (3,842,048)
//   ss   [2][256] f32          @ 158457856  (2,048)
//   bias [256] f32             @ 158459904  (1,024)

#define BB 4
#define CIN 128
#define COUT 256
#define EE 30000
#define BN 64
#define NTILES 469          // ceil(30000/64)
#define BC 64
#define KCH 320             // 5*BC K-values per chunk
#define PITCH 328
#define NBLK (NTILES * BB)  // 1876
#define GRID1 1880          // swizzled 1D grid for conv kernels

typedef __attribute__((ext_vector_type(8))) short bf16x8;
typedef __attribute__((ext_vector_type(4))) float f32x4;

static __device__ __forceinline__ float blo(unsigned u) {
    union { unsigned u; float f; } v; v.u = u << 16; return v.f;
}
static __device__ __forceinline__ float bhi(unsigned u) {
    union { unsigned u; float f; } v; v.u = u & 0xffff0000u; return v.f;
}
static __device__ __forceinline__ unsigned pk2(float lo, float hi) {
    __hip_bfloat162 h = __float22bfloat162_rn(float2{lo, hi});   // v_cvt_pk_bf16_f32
    union { __hip_bfloat162 h; unsigned u; } v; v.h = h; return v.u;
}
static __device__ __forceinline__ unsigned short bf1(float f) {
    __hip_bfloat16 h = __float2bfloat16(f);
    union { __hip_bfloat16 h; unsigned short u; } v; v.h = h; return v.u;
}

// ---------------- transpose + cast: x[B,C,E] f32 -> xT[B,E,C] bf16 ----------
__global__ __launch_bounds__(256) void k_transpose(const float* __restrict__ x,
                                                   unsigned short* __restrict__ xT) {
    __shared__ float tile[64][CIN + 1];
    const int t = threadIdx.x;
    const int e0 = blockIdx.x * 64;
    const int b = blockIdx.y;
    const int el = t & 63;
    const bool ok = (e0 + el) < EE;
    const float* xb = x + (size_t)b * CIN * EE;
#pragma unroll
    for (int cc = 0; cc < CIN / 4; ++cc) {
        const int c = cc * 4 + (t >> 6);
        tile[el][c] = ok ? xb[(size_t)c * EE + e0 + el] : 0.f;
    }
    __syncthreads();
    const int el2 = t >> 2, cq = t & 3;
    if (e0 + el2 < EE) {
        unsigned ov[16];
#pragma unroll
        for (int i = 0; i < 16; ++i)
            ov[i] = pk2(tile[el2][cq * 32 + 2 * i], tile[el2][cq * 32 + 2 * i + 1]);
        int4* dst = (int4*)(xT + ((size_t)b * EE + e0 + el2) * CIN + cq * 32);
#pragma unroll
        for (int j = 0; j < 4; ++j)
            dst[j] = make_int4((int)ov[4 * j], (int)ov[4 * j + 1], (int)ov[4 * j + 2], (int)ov[4 * j + 3]);
    }
}

// ------------- W repack: W[m][c][k] f32 -> Wf[G/32][m][G%32] bf16 -----------
// K-order: G = chunk*KCH + k*BC + (c - chunk*BC), chunk = c/BC
// ss != null: fold BN scale (k<3: sc_c, else |sc_c|)
__global__ __launch_bounds__(256) void k_wprep(const float* __restrict__ W,
                                               unsigned short* __restrict__ Wf,
                                               const float* __restrict__ ss,
                                               int C, int K) {
    const int id = blockIdx.x * 256 + threadIdx.x;
    if (id >= 256 * K) return;
    const int m = id / K;
    const int G = id % K;
    const int chunk = G / KCH;
    const int r = G % KCH;
    const int k = r / BC;
    const int c = chunk * BC + (r % BC);
    float val = W[((size_t)m * C + c) * 5 + k];
    if (ss) {
        const float sc = ss[c];
        val *= (k < 3) ? sc : fabsf(sc);
    }
    Wf[((size_t)(G / 32) * 256 + m) * 32 + (G % 32)] = bf1(val);
}

// -------------------------- BN stats finalize -------------------------------
__global__ __launch_bounds__(256) void k_stats(const float* __restrict__ partials,
                                               const float* __restrict__ gamma,
                                               const float* __restrict__ beta,
                                               float* __restrict__ ss) {
    const int ch = blockIdx.x;
    const int t = threadIdx.x;
    float s = 0.f, q = 0.f;
    for (int i = t; i < NBLK; i += 256) {
        s += partials[(size_t)i * 512 + ch];
        q += partials[(size_t)i * 512 + 256 + ch];
    }
    __shared__ float ls[256], lq[256];
    ls[t] = s; lq[t] = q;
    __syncthreads();
    for (int off = 128; off > 0; off >>= 1) {
        if (t < off) { ls[t] += ls[t + off]; lq[t] += lq[t + off]; }
        __syncthreads();
    }
    if (t == 0) {
        const float inv = 1.f / (float)(BB * EE);
        const float mean = ls[0] * inv;
        const float var = lq[0] * inv - mean * mean;
        const float sc = gamma[ch] * rsqrtf(var + 1e-5f);
        ss[ch] = sc;
        ss[COUT + ch] = beta[ch] - mean * sc;
    }
}

// ---------------- bias[o] = sum_c sh_c * (W1[o,c,0] + 2W1[o,c,1] + 2W1[o,c,2])
__global__ __launch_bounds__(256) void k_bias(const float* __restrict__ W1,
                                              const float* __restrict__ ss,
                                              float* __restrict__ bias) {
    const int o = blockIdx.x, t = threadIdx.x;
    const float sh = ss[COUT + t];
    const float* wr = W1 + ((size_t)o * COUT + t) * 5;
    float v = sh * (wr[0] + 2.f * (wr[1] + wr[2]));
    __shared__ float red[256];
    red[t] = v;
    __syncthreads();
    for (int off = 128; off > 0; off >>= 1) {
        if (t < off) red[t] += red[t + off];
        __syncthreads();
    }
    if (t == 0) bias[o] = red[0];
}

// --------------------------- fused mesh-conv GEMM ---------------------------
// BM=256 (all out channels), BN=64 edges, 4 waves each 64x64.
// IS1=0: conv0 (writes x1 frag-blocked, rT=relu(x1), stat partials)
// IS1=1: conv1 (gathers raw rT; affine pre-folded into Wf/bias; adds x1, relu)
template <int C, int CHUNKS, int IS1>
__global__ __launch_bounds__(256, 2) void k_conv(
    const unsigned short* __restrict__ xin,
    const int* __restrict__ gmm,
    const unsigned short* __restrict__ Wf,
    const float* __restrict__ bias,
    unsigned short* __restrict__ x1,
    unsigned short* __restrict__ rT,
    float* __restrict__ partials,
    float* __restrict__ out) {
    __shared__ unsigned short f_lds[64 * PITCH];
    const int t = threadIdx.x;
    const int w = t >> 6, lane = t & 63;
    const int ml = lane & 15, g = lane >> 4;
    // XCD batch-affinity decode: XCD(i) ~ i%8 round-robin; batch b -> XCDs {2b,2b+1}
    const int i = blockIdx.x;
    const int b = (i & 7) >> 1;
    const int tile = ((i >> 3) << 1) | (i & 1);
    if (tile >= NTILES) return;
    const int e0 = tile * BN;

    // build roles: 4 threads per edge, each owns 16 channels of each chunk
    const int be = t >> 2, bq = t & 3;
    const int eb = e0 + be;
    const int ec = (eb < EE) ? eb : 0;
    const int4 nb = *(const int4*)(gmm + ((size_t)b * EE + ec) * 4);

    const unsigned short* xb = xin + (size_t)b * EE * C;
    const unsigned short* rowc = xb + (size_t)ec * C;
    const unsigned short* row1 = xb + (size_t)nb.x * C;
    const unsigned short* row2 = xb + (size_t)nb.y * C;
    const unsigned short* row3 = xb + (size_t)nb.z * C;
    const unsigned short* row4 = xb + (size_t)nb.w * C;

    f32x4 acc[4][4];
#pragma unroll
    for (int ii = 0; ii < 4; ++ii)
#pragma unroll
        for (int jj = 0; jj < 4; ++jj)
            acc[ii][jj] = (f32x4){0.f, 0.f, 0.f, 0.f};

    int4 bufA[10], bufB[10];

    auto stage = [&](int chunk, int4* dst) {
        const int cb = chunk * BC + bq * 16;
        dst[0] = *(const int4*)(row1 + cb); dst[1] = *(const int4*)(row1 + cb + 8);
        dst[2] = *(const int4*)(row3 + cb); dst[3] = *(const int4*)(row3 + cb + 8);
        dst[4] = *(const int4*)(row2 + cb); dst[5] = *(const int4*)(row2 + cb + 8);
        dst[6] = *(const int4*)(row4 + cb); dst[7] = *(const int4*)(row4 + cb + 8);
        dst[8] = *(const int4*)(rowc + cb); dst[9] = *(const int4*)(rowc + cb + 8);
    };

    auto step = [&](int chunk, const int4* cur, int4* nxt, bool donext) {
        // issue next chunk's gathers FIRST: by the time the MFMA phase's W-load
        // waits drain vmcnt, these have had build+barrier+ds_write of latency.
        if (donext) stage(chunk + 1, nxt);

        const unsigned* u13a = (const unsigned*)&cur[0];
        const unsigned* u13b = (const unsigned*)&cur[2];
        const unsigned* u24a = (const unsigned*)&cur[4];
        const unsigned* u24b = (const unsigned*)&cur[6];
        const unsigned* uc   = (const unsigned*)&cur[8];
        unsigned o1[8], o2[8], o3[8], o4[8];
#pragma unroll
        for (int j = 0; j < 8; ++j) {
            const float a0 = blo(u13a[j]), a1 = bhi(u13a[j]);
            const float b0 = blo(u13b[j]), b1 = bhi(u13b[j]);
            o1[j] = pk2(a0 + b0, a1 + b1);
            o3[j] = pk2(fabsf(a0 - b0), fabsf(a1 - b1));
        }
#pragma unroll
        for (int j = 0; j < 8; ++j) {
            const float a0 = blo(u24a[j]), a1 = bhi(u24a[j]);
            const float b0 = blo(u24b[j]), b1 = bhi(u24b[j]);
            o2[j] = pk2(a0 + b0, a1 + b1);
            o4[j] = pk2(fabsf(a0 - b0), fabsf(a1 - b1));
        }

        __syncthreads();   // previous chunk's MFMA reads done
        {
            unsigned short* bp = &f_lds[be * PITCH + bq * 16];
            *(int4*)(bp + 0 * BC)     = make_int4((int)uc[0], (int)uc[1], (int)uc[2], (int)uc[3]);
            *(int4*)(bp + 0 * BC + 8) = make_int4((int)uc[4], (int)uc[5], (int)uc[6], (int)uc[7]);
            *(int4*)(bp + 1 * BC)     = make_int4((int)o1[0], (int)o1[1], (int)o1[2], (int)o1[3]);
            *(int4*)(bp + 1 * BC + 8) = make_int4((int)o1[4], (int)o1[5], (int)o1[6], (int)o1[7]);
            *(int4*)(bp + 2 * BC)     = make_int4((int)o2[0], (int)o2[1], (int)o2[2], (int)o2[3]);
            *(int4*)(bp + 2 * BC + 8) = make_int4((int)o2[4], (int)o2[5], (int)o2[6], (int)o2[7]);
            *(int4*)(bp + 3 * BC)     = make_int4((int)o3[0], (int)o3[1], (int)o3[2], (int)o3[3]);
            *(int4*)(bp + 3 * BC + 8) = make_int4((int)o3[4], (int)o3[5], (int)o3[6], (int)o3[7]);
            *(int4*)(bp + 4 * BC)     = make_int4((int)o4[0], (int)o4[1], (int)o4[2], (int)o4[3]);
            *(int4*)(bp + 4 * BC + 8) = make_int4((int)o4[4], (int)o4[5], (int)o4[6], (int)o4[7]);
        }
        __syncthreads();

        const unsigned short* wp = Wf + (size_t)chunk * (KCH / 32) * COUT * 32;
#pragma unroll 2
        for (int kk = 0; kk < KCH / 32; ++kk) {
            union { int4 i; bf16x8 h; } af[4], bfr[4];
#pragma unroll
            for (int fm = 0; fm < 4; ++fm)
                af[fm].i = *(const int4*)(wp + ((size_t)kk * COUT + (w * 64 + fm * 16 + ml)) * 32 + g * 8);
#pragma unroll
            for (int fn = 0; fn < 4; ++fn)
                bfr[fn].i = *(const int4*)&f_lds[(fn * 16 + ml) * PITCH + kk * 32 + g * 8];
#pragma unroll
            for (int fm = 0; fm < 4; ++fm)
#pragma unroll
                for (int fn = 0; fn < 4; ++fn)
                    acc[fm][fn] = __builtin_amdgcn_mfma_f32_16x16x32_bf16(af[fm].h, bfr[fn].h, acc[fm][fn], 0, 0, 0);
        }
    };

    stage(0, bufA);
#pragma unroll 1
    for (int cp = 0; cp < CHUNKS / 2; ++cp) {
        step(2 * cp, bufA, bufB, true);
        step(2 * cp + 1, bufB, bufA, (2 * cp + 2) < CHUNKS);
    }

    // ------------------------------ epilogue --------------------------------
    const size_t fragbase = (((size_t)b * NTILES + tile) * 4 + w) * 16;
    if (!IS1) {
        float ks[4][4], kq[4][4];
#pragma unroll
        for (int fm = 0; fm < 4; ++fm)
#pragma unroll
            for (int r = 0; r < 4; ++r) { ks[fm][r] = 0.f; kq[fm][r] = 0.f; }
#pragma unroll
        for (int fm = 0; fm < 4; ++fm) {
#pragma unroll
            for (int fn = 0; fn < 4; ++fn) {
                const int fi = fm * 4 + fn;
                uint2 pk;
                pk.x = pk2(acc[fm][fn][0], acc[fm][fn][1]);
                pk.y = pk2(acc[fm][fn][2], acc[fm][fn][3]);
                *(uint2*)(x1 + (fragbase + fi) * 256 + lane * 4) = pk;   // coalesced
                const int e = e0 + fn * 16 + ml;
                float rv0 = fmaxf(acc[fm][fn][0], 0.f), rv1 = fmaxf(acc[fm][fn][1], 0.f);
                float rv2 = fmaxf(acc[fm][fn][2], 0.f), rv3 = fmaxf(acc[fm][fn][3], 0.f);
                if (e < EE) {
                    uint2 pr;
                    pr.x = pk2(rv0, rv1);
                    pr.y = pk2(rv2, rv3);
                    *(uint2*)(rT + ((size_t)b * EE + e) * COUT + w * 64 + fm * 16 + g * 4) = pr;
                } else {
                    rv0 = rv1 = rv2 = rv3 = 0.f;
                }
                ks[fm][0] += rv0; kq[fm][0] += rv0 * rv0;
                ks[fm][1] += rv1; kq[fm][1] += rv1 * rv1;
                ks[fm][2] += rv2; kq[fm][2] += rv2 * rv2;
                ks[fm][3] += rv3; kq[fm][3] += rv3 * rv3;
            }
        }
        // reduce over the 16 ml-lanes (same channel set per (w,g))
#pragma unroll
        for (int fm = 0; fm < 4; ++fm) {
#pragma unroll
            for (int r = 0; r < 4; ++r) {
#pragma unroll
                for (int m = 1; m < 16; m <<= 1) {
                    ks[fm][r] += __shfl_xor(ks[fm][r], m);
                    kq[fm][r] += __shfl_xor(kq[fm][r], m);
                }
            }
        }
        if (ml == 0) {
            float* pp = partials + ((size_t)b * NTILES + tile) * 512;
#pragma unroll
            for (int fm = 0; fm < 4; ++fm) {
                const int ch = w * 64 + fm * 16 + g * 4;
                *(float4*)(pp + ch)       = make_float4(ks[fm][0], ks[fm][1], ks[fm][2], ks[fm][3]);
                *(float4*)(pp + 256 + ch) = make_float4(kq[fm][0], kq[fm][1], kq[fm][2], kq[fm][3]);
            }
        }
    } else {
#pragma unroll
        for (int fm = 0; fm < 4; ++fm) {
            const int chb = w * 64 + fm * 16 + g * 4;
            const float4 bv = *(const float4*)(bias + chb);
#pragma unroll
            for (int fn = 0; fn < 4; ++fn) {
                const int fi = fm * 4 + fn;
                const uint2 pk = *(const uint2*)(x1 + (fragbase + fi) * 256 + lane * 4);
                const int e = e0 + fn * 16 + ml;
                if (e < EE) {
                    float* op = out + ((size_t)b * COUT + chb) * EE + e;
                    op[0]              = fmaxf(acc[fm][fn][0] + bv.x + blo(pk.x), 0.f);
                    op[(size_t)EE]     = fmaxf(acc[fm][fn][1] + bv.y + bhi(pk.x), 0.f);
                    op[(size_t)2 * EE] = fmaxf(acc[fm][fn][2] + bv.z + blo(pk.y), 0.f);
                    op[(size_t)3 * EE] = fmaxf(acc[fm][fn][3] + bv.w + bhi(pk.y), 0.f);
                }
            }
        }
    }
}

extern "C" void kernel_launch(void* const* d_in, const int* in_sizes, int n_in,
                              void* d_out, int out_size, void* d_ws, size_t ws_size,
                              hipStream_t stream) {
    const float* x = (const float*)d_in[0];
    const int* gmm = (const int*)d_in[1];
    const float* W0 = (const float*)d_in[2];
    const float* gamma = (const float*)d_in[3];
    const float* beta = (const float*)d_in[4];
    const float* W1 = (const float*)d_in[5];
    float* out = (float*)d_out;

    char* ws = (char*)d_ws;
    unsigned short* xT  = (unsigned short*)(ws);
    unsigned short* Wf0 = (unsigned short*)(ws + 30720000);
    unsigned short* Wf1 = (unsigned short*)(ws + 31047680);
    unsigned short* x1  = (unsigned short*)(ws + 31703040);
    unsigned short* rT  = (unsigned short*)(ws + 93175808);
    float* partials     = (float*)(ws + 154615808);
    float* ss           = (float*)(ws + 158457856);
    float* bias         = (float*)(ws + 158459904);

    k_transpose<<<dim3(NTILES, BB), 256, 0, stream>>>(x, xT);
    k_wprep<<<dim3(640), 256, 0, stream>>>(W0, Wf0, nullptr, CIN, 640);
    k_conv<CIN, 2, 0><<<dim3(GRID1), 256, 0, stream>>>(
        xT, gmm, Wf0, nullptr, x1, rT, partials, nullptr);
    k_stats<<<dim3(256), 256, 0, stream>>>(partials, gamma, beta, ss);
    k_bias<<<dim3(256), 256, 0, stream>>>(W1, ss, bias);
    k_wprep<<<dim3(1280), 256, 0, stream>>>(W1, Wf1, ss, COUT, 1280);
    k_conv<COUT, 4, 1><<<dim3(GRID1), 256, 0, stream>>>(
        rT, gmm, Wf1, bias, x1, nullptr, nullptr, out);
}